// Round 5
// baseline (280.043 us; speedup 1.0000x reference)
//
#include <hip/hip_runtime.h>

typedef unsigned int uint;
typedef unsigned short ushort;
typedef __attribute__((ext_vector_type(8))) short short8;
typedef __attribute__((ext_vector_type(4))) float f32x4;
typedef __attribute__((ext_vector_type(4))) uint uint4w;

#define T_LEN 32768
#define EMB 300
#define HID 256
#define NCOLS 4096

__device__ __forceinline__ ushort f2bf(float f) {
  uint u = __float_as_uint(f);
  return (ushort)((u + 0x7fffu + ((u >> 16) & 1u)) >> 16);
}
__device__ __forceinline__ float bf2f(ushort u) {
  return __uint_as_float(((uint)u) << 16);
}
__device__ __forceinline__ float sigm(float x) { return 1.f / (1.f + __expf(-x)); }
__device__ __forceinline__ float tanh_(float x) { return 2.f / (1.f + __expf(-2.f * x)) - 1.f; }

__device__ __forceinline__ void gload_lds16(const void* g, void* l) {
  __builtin_amdgcn_global_load_lds((const __attribute__((address_space(1))) void*)g,
                                   (__attribute__((address_space(3))) void*)l, 16, 0, 0);
}

// ---------------- prep: bf16 conversions + embedding gather ----------------
__global__ void prep_kernel(const float* __restrict__ emb,
                            const float* __restrict__ wihf, const float* __restrict__ whhf,
                            const float* __restrict__ bihf, const float* __restrict__ bhhf,
                            const float* __restrict__ wihb, const float* __restrict__ whhb,
                            const float* __restrict__ bihb, const float* __restrict__ bhhb,
                            const int* __restrict__ seq,
                            ushort* __restrict__ X, ushort* __restrict__ Wih,
                            ushort* __restrict__ Whh, float* __restrict__ bias) {
  const int NX = T_LEN * 40;      // 32768 rows x 40 groups of 8 k (K padded to 320)
  const int NWIH = 2048 * 40;
  const int NWHH = 2048 * 32;
  const int NB = 2048;
  const int total = NX + NWIH + NWHH + NB;
  for (int t = blockIdx.x * blockDim.x + threadIdx.x; t < total; t += gridDim.x * blockDim.x) {
    if (t < NX) {
      int r = t / 40, k8 = t % 40, k = k8 * 8;
      int col = r >> 3, j = r & 7;
      int tok = (col == 0) ? j : (col * 8 - 1 + j);   // matches reference idx
      const float* src = emb + (long)seq[tok] * EMB + k;
      alignas(16) ushort tmp[8];
#pragma unroll
      for (int i = 0; i < 8; ++i) tmp[i] = (k + i < EMB) ? f2bf(src[i]) : (ushort)0;
      *(uint4w*)(X + (long)r * 320 + k) = *(const uint4w*)tmp;
    } else if (t < NX + NWIH) {
      int t2 = t - NX;
      int n = t2 / 40, k8 = t2 % 40, k = k8 * 8;
      const float* src = ((n < 1024) ? wihf : wihb) + (long)(n & 1023) * EMB + k;
      alignas(16) ushort tmp[8];
#pragma unroll
      for (int i = 0; i < 8; ++i) tmp[i] = (k + i < EMB) ? f2bf(src[i]) : (ushort)0;
      *(uint4w*)(Wih + (long)n * 320 + k) = *(const uint4w*)tmp;
    } else if (t < NX + NWIH + NWHH) {
      int t3 = t - NX - NWIH;
      int n = t3 / 32, k8 = t3 % 32, k = k8 * 8;
      const float* src = ((n < 1024) ? whhf : whhb) + (long)(n & 1023) * HID + k;
      alignas(16) ushort tmp[8];
#pragma unroll
      for (int i = 0; i < 8; ++i) tmp[i] = f2bf(src[i]);
      *(uint4w*)(Whh + (long)n * 256 + k) = *(const uint4w*)tmp;
    } else {
      int n = t - NX - NWIH - NWHH;
      bias[n] = (n < 1024) ? (bihf[n] + bhhf[n]) : (bihb[n - 1024] + bhhb[n - 1024]);
    }
  }
}

// ---------------- K1: xg = X @ Wih^T + bias  (M=32768,K=320,N=2048) ----------------
__global__ void gemm_xg_kernel(const ushort* __restrict__ X, const ushort* __restrict__ Wih,
                               const float* __restrict__ bias, ushort* __restrict__ xg) {
  __shared__ ushort a_lds[2][128 * 32];
  const int tid = threadIdx.x;
  const int lane = tid & 63, w = tid >> 6;
  const int wr = w >> 1, wc = w & 1;
  const int qrow = lane >> 4, ln = lane & 15;
  const int m0 = blockIdx.x * 128, n0 = blockIdx.y * 128;

  auto stage = [&](int buf, int kt) {
#pragma unroll
    for (int q = 0; q < 2; ++q) {
      int byteoff = w * 2048 + q * 1024 + lane * 16;
      int row = byteoff >> 6, koff = byteoff & 63;
      const char* src = (const char*)X + (long)(m0 + row) * 640 + kt * 64 + koff;
      void* dst = (char*)&a_lds[buf][0] + w * 2048 + q * 1024;  // wave-uniform base
      gload_lds16(src, dst);
    }
  };

  // B fragment base for this lane (row-major Wih, K=320)
  const ushort* wb = Wih + (long)(n0 + wc * 64 + ln) * 320 + qrow * 8;
  auto loadB = [&](short8 (&dst)[4], int kt) {
#pragma unroll
    for (int nt = 0; nt < 4; ++nt)
      dst[nt] = *(const short8*)(wb + nt * 16 * 320 + kt * 32);
  };

  const f32x4 fzero = {0.f, 0.f, 0.f, 0.f};
  f32x4 acc[4][4];
#pragma unroll
  for (int i = 0; i < 4; ++i)
#pragma unroll
    for (int jj = 0; jj < 4; ++jj) acc[i][jj] = fzero;

  auto gemmK = [&](short8 (&b)[4], int buf) {
    short8 a[4];
#pragma unroll
    for (int rt = 0; rt < 4; ++rt)
      a[rt] = *(const short8*)&a_lds[buf][(wr * 64 + rt * 16 + ln) * 32 + qrow * 8];
#pragma unroll
    for (int rt = 0; rt < 4; ++rt)
#pragma unroll
      for (int nt = 0; nt < 4; ++nt)
        acc[rt][nt] = __builtin_amdgcn_mfma_f32_16x16x32_bf16(a[rt], b[nt], acc[rt][nt], 0, 0, 0);
  };

  short8 bA[4], bB[4];
  stage(0, 0);
  loadB(bA, 0);
#pragma unroll 1
  for (int kt2 = 0; kt2 < 5; ++kt2) {
    const int kt = kt2 * 2;
    __syncthreads();                 // stage(kt) landed everywhere (implicit vmcnt drain)
    if (kt < 9) stage(1, kt + 1);    // (kt+1)&1 == 1
    loadB(bB, kt + 1);               // pipelined: in flight during even-kt MFMAs
    gemmK(bA, 0);
    __syncthreads();                 // stage(kt+1) landed
    if (kt + 2 < 10) stage(0, kt + 2);
    if (kt2 < 4) loadB(bA, kt + 2);  // pipelined: in flight during odd-kt MFMAs
    gemmK(bB, 1);
  }

  // epilogue: repack through LDS (reuse a_lds[0]) -> coalesced dwordx4 stores
  ushort* sbuf = &a_lds[0][0];   // 32 x 128 ushort = 8 KB per chunk
  float bv[4];
#pragma unroll
  for (int nt = 0; nt < 4; ++nt) bv[nt] = bias[n0 + wc * 64 + nt * 16 + ln];
#pragma unroll
  for (int R = 0; R < 4; ++R) {
    __syncthreads();   // previous chunk's reads done / k-loop reads done
#pragma unroll
    for (int nt = 0; nt < 4; ++nt)
#pragma unroll
      for (int r = 0; r < 4; ++r)
        sbuf[(wr * 16 + qrow * 4 + r) * 128 + wc * 64 + nt * 16 + ln] = f2bf(acc[R][nt][r] + bv[nt]);
    __syncthreads();
#pragma unroll
    for (int p = 0; p < 2; ++p) {
      int row = p * 16 + (tid >> 4);
      int c0 = (tid & 15) * 8;
      uint4w v = *(uint4w*)&sbuf[row * 128 + c0];
      *(uint4w*)&xg[(long)(m0 + (row >> 4) * 64 + R * 16 + (row & 15)) * 2048 + n0 + c0] = v;
    }
  }
}

// ---------------- K2: fused masked LSTM recurrence, one direction per block ----------------
// grid 256 = {d in 0..1} x {cg in 0..127}; 32 columns per block; 512 threads (8 waves)
// Whh stays in L2 (1 MB, shared by all CUs); b-fragments software-pipelined (2-deep ping-pong)
__global__ __launch_bounds__(512, 2) void lstm_kernel(const ushort* __restrict__ xg,
                                                      const ushort* __restrict__ Whh,
                                                      float* __restrict__ out) {
  __shared__ ushort h_lds[32][264];          // [col][hid], padded
  __shared__ ushort xg_lds[2][32][1024];     // double-buffered step tile (128 KB)
  const int tid = threadIdx.x;
  const int lane = tid & 63, w = tid >> 6;   // w = hid-slice owner (32 hid per wave)
  const int qrow = lane >> 4, ln = lane & 15;
  const int bid = blockIdx.x;
  const int d = bid >> 7, cg = bid & 127;

  // per-lane base into Whh; fragment (ks,g,q) at +g*65536 + q*4096 + ks*32 elements
  const ushort* wbase = Whh + (long)(d * 1024 + w * 32 + ln) * 256 + qrow * 8;

  float c_st[2][2][4], h_st[2][2][4];
#pragma unroll
  for (int rt = 0; rt < 2; ++rt)
#pragma unroll
    for (int q = 0; q < 2; ++q)
#pragma unroll
      for (int r = 0; r < 4; ++r) { c_st[rt][q][r] = 0.f; h_st[rt][q][r] = 0.f; }

  auto stage = [&](int buf, int j) {
#pragma unroll
    for (int q = 0; q < 8; ++q) {
      int byteoff = w * 8192 + q * 1024 + lane * 16;
      int cloc = byteoff >> 11, noff = byteoff & 2047;
      const char* src = (const char*)xg + (long)((cg * 32 + cloc) * 8 + j) * 4096 + d * 2048 + noff;
      void* dst = (char*)&xg_lds[0][0][0] + buf * 65536 + w * 8192 + q * 1024;  // wave-uniform
      gload_lds16(src, dst);
    }
  };

  const f32x4 fzero = {0.f, 0.f, 0.f, 0.f};

  stage(0, d ? 7 : 0);

#pragma unroll 1
  for (int it = 0; it < 8; ++it) {
    __syncthreads();   // implicit full drain: stage(it) landed everywhere; h_lds(it-1) visible
    if (it < 7) stage((it + 1) & 1, d ? (6 - it) : (it + 1));  // prefetch stays in flight
    const int buf = it & 1;

    f32x4 acc[4][2][2];  // [gate][q(hid-16-block)][row-tile]
#pragma unroll
    for (int g = 0; g < 4; ++g)
#pragma unroll
      for (int q = 0; q < 2; ++q)
#pragma unroll
        for (int rt = 0; rt < 2; ++rt) acc[g][q][rt] = fzero;

    if (it > 0) {  // h==0 at it==0, skip GEMM
      auto loadB = [&](short8 (&dst)[4][2], int ks) {
#pragma unroll
        for (int g = 0; g < 4; ++g)
#pragma unroll
          for (int q = 0; q < 2; ++q)
            dst[g][q] = *(const short8*)(wbase + g * 65536 + q * 4096 + ks * 32);
      };
      auto gemmK = [&](short8 (&b)[4][2], int ks) {
        short8 a0 = *(const short8*)&h_lds[ln][ks * 32 + qrow * 8];
        short8 a1 = *(const short8*)&h_lds[16 + ln][ks * 32 + qrow * 8];
#pragma unroll
        for (int g = 0; g < 4; ++g)
#pragma unroll
          for (int q = 0; q < 2; ++q) {
            acc[g][q][0] = __builtin_amdgcn_mfma_f32_16x16x32_bf16(a0, b[g][q], acc[g][q][0], 0, 0, 0);
            acc[g][q][1] = __builtin_amdgcn_mfma_f32_16x16x32_bf16(a1, b[g][q], acc[g][q][1], 0, 0, 0);
          }
      };
      // 2-deep software pipeline over ks, statically-indexed ping-pong buffers
      short8 bA[4][2], bB[4][2];
      loadB(bA, 0);
      loadB(bB, 1);
      gemmK(bA, 0); loadB(bA, 2);
      gemmK(bB, 1); loadB(bB, 3);
      gemmK(bA, 2); loadB(bA, 4);
      gemmK(bB, 3); loadB(bB, 5);
      gemmK(bA, 4); loadB(bA, 6);
      gemmK(bB, 5); loadB(bB, 7);
      gemmK(bA, 6);
      gemmK(bB, 7);
    }
    // LDS-only barrier (do NOT drain vmcnt -> keep xg prefetch in flight):
    asm volatile("s_waitcnt lgkmcnt(0)" ::: "memory");
    __builtin_amdgcn_s_barrier();

    // cell: lane holds all 4 gates of its cells (cc = rt*16+qrow*4+r, hid = w*32+q*16+ln)
    const bool mstep = d ? (it == 0) : (it == 7);
#pragma unroll
    for (int rt = 0; rt < 2; ++rt)
#pragma unroll
      for (int q = 0; q < 2; ++q)
#pragma unroll
        for (int r = 0; r < 4; ++r) {
          int cc = rt * 16 + qrow * 4 + r;
          int hid = w * 32 + q * 16 + ln;
          float pi = acc[0][q][rt][r] + bf2f(xg_lds[buf][cc][hid]);
          float pf = acc[1][q][rt][r] + bf2f(xg_lds[buf][cc][256 + hid]);
          float pg = acc[2][q][rt][r] + bf2f(xg_lds[buf][cc][512 + hid]);
          float po = acc[3][q][rt][r] + bf2f(xg_lds[buf][cc][768 + hid]);
          float cn = sigm(pf) * c_st[rt][q][r] + sigm(pi) * tanh_(pg);
          float hn = sigm(po) * tanh_(cn);
          bool skip = mstep && (cg == 0) && (cc == 0);  // only masked cell: col 0, j==7
          if (!skip) { c_st[rt][q][r] = cn; h_st[rt][q][r] = hn; }
          h_lds[cc][hid] = f2bf(h_st[rt][q][r]);
        }
  }

#pragma unroll
  for (int rt = 0; rt < 2; ++rt)
#pragma unroll
    for (int q = 0; q < 2; ++q)
#pragma unroll
      for (int r = 0; r < 4; ++r) {
        int cc = rt * 16 + qrow * 4 + r;
        int hid = w * 32 + q * 16 + ln;
        out[(long)(cg * 32 + cc) * 512 + d * 256 + hid] = h_st[rt][q][r];
      }
}

extern "C" void kernel_launch(void* const* d_in, const int* in_sizes, int n_in,
                              void* d_out, int out_size, void* d_ws, size_t ws_size,
                              hipStream_t stream) {
  const float* emb  = (const float*)d_in[0];
  const float* wihf = (const float*)d_in[1];
  const float* whhf = (const float*)d_in[2];
  const float* bihf = (const float*)d_in[3];
  const float* bhhf = (const float*)d_in[4];
  const float* wihb = (const float*)d_in[5];
  const float* whhb = (const float*)d_in[6];
  const float* bihb = (const float*)d_in[7];
  const float* bhhb = (const float*)d_in[8];
  const int*   seq  = (const int*)d_in[9];
  float* out = (float*)d_out;

  char* ws = (char*)d_ws;
  // ws layout (bytes): xg 134217728 | X 20971520 | Wih 1310720 | Whh 1048576 | bias 8192
  ushort* xg   = (ushort*)(ws);
  ushort* X    = (ushort*)(ws + 134217728);
  ushort* Wih  = (ushort*)(ws + 155189248);
  ushort* Whh  = (ushort*)(ws + 156499968);
  float*  bias = (float*)(ws + 157548544);

  prep_kernel<<<dim3(1024), dim3(256), 0, stream>>>(emb, wihf, whhf, bihf, bhhf,
                                                    wihb, whhb, bihb, bhhb, seq,
                                                    X, Wih, Whh, bias);
  gemm_xg_kernel<<<dim3(256, 16), dim3(256), 0, stream>>>(X, Wih, bias, xg);
  lstm_kernel<<<dim3(256), dim3(512), 0, stream>>>(xg, Whh, out);
}

// Round 7
// 276.376 us; speedup vs baseline: 1.0133x; 1.0133x over previous
//
#include <hip/hip_runtime.h>

typedef unsigned int uint;
typedef unsigned short ushort;
typedef __attribute__((ext_vector_type(8))) short short8;
typedef __attribute__((ext_vector_type(4))) float f32x4;
typedef __attribute__((ext_vector_type(4))) uint uint4w;

#define T_LEN 32768
#define EMB 300
#define HID 256
#define NCOLS 4096

__device__ __forceinline__ ushort f2bf(float f) {
  uint u = __float_as_uint(f);
  return (ushort)((u + 0x7fffu + ((u >> 16) & 1u)) >> 16);
}
__device__ __forceinline__ float bf2f(ushort u) {
  return __uint_as_float(((uint)u) << 16);
}
__device__ __forceinline__ float sigm(float x) { return 1.f / (1.f + __expf(-x)); }
__device__ __forceinline__ float tanh_(float x) { return 2.f / (1.f + __expf(-2.f * x)) - 1.f; }

__device__ __forceinline__ void gload_lds16(const void* g, void* l) {
  __builtin_amdgcn_global_load_lds((const __attribute__((address_space(1))) void*)g,
                                   (__attribute__((address_space(3))) void*)l, 16, 0, 0);
}

// ---------------- prep: bf16 conversions + embedding gather ----------------
__global__ void prep_kernel(const float* __restrict__ emb,
                            const float* __restrict__ wihf, const float* __restrict__ whhf,
                            const float* __restrict__ bihf, const float* __restrict__ bhhf,
                            const float* __restrict__ wihb, const float* __restrict__ whhb,
                            const float* __restrict__ bihb, const float* __restrict__ bhhb,
                            const int* __restrict__ seq,
                            ushort* __restrict__ X, ushort* __restrict__ Wih,
                            ushort* __restrict__ Whh, float* __restrict__ bias) {
  const int NX = T_LEN * 40;      // 32768 rows x 40 groups of 8 k (K padded to 320)
  const int NWIH = 2048 * 40;
  const int NWHH = 2048 * 32;
  const int NB = 2048;
  const int total = NX + NWIH + NWHH + NB;
  for (int t = blockIdx.x * blockDim.x + threadIdx.x; t < total; t += gridDim.x * blockDim.x) {
    if (t < NX) {
      int r = t / 40, k8 = t % 40, k = k8 * 8;
      int col = r >> 3, j = r & 7;
      int tok = (col == 0) ? j : (col * 8 - 1 + j);   // matches reference idx
      const float* src = emb + (long)seq[tok] * EMB + k;
      alignas(16) ushort tmp[8];
#pragma unroll
      for (int i = 0; i < 8; ++i) tmp[i] = (k + i < EMB) ? f2bf(src[i]) : (ushort)0;
      *(uint4w*)(X + (long)r * 320 + k) = *(const uint4w*)tmp;
    } else if (t < NX + NWIH) {
      int t2 = t - NX;
      int n = t2 / 40, k8 = t2 % 40, k = k8 * 8;
      const float* src = ((n < 1024) ? wihf : wihb) + (long)(n & 1023) * EMB + k;
      alignas(16) ushort tmp[8];
#pragma unroll
      for (int i = 0; i < 8; ++i) tmp[i] = (k + i < EMB) ? f2bf(src[i]) : (ushort)0;
      *(uint4w*)(Wih + (long)n * 320 + k) = *(const uint4w*)tmp;
    } else if (t < NX + NWIH + NWHH) {
      int t3 = t - NX - NWIH;
      int n = t3 / 32, k8 = t3 % 32, k = k8 * 8;
      const float* src = ((n < 1024) ? whhf : whhb) + (long)(n & 1023) * HID + k;
      alignas(16) ushort tmp[8];
#pragma unroll
      for (int i = 0; i < 8; ++i) tmp[i] = f2bf(src[i]);
      *(uint4w*)(Whh + (long)n * 256 + k) = *(const uint4w*)tmp;
    } else {
      int n = t - NX - NWIH - NWHH;
      bias[n] = (n < 1024) ? (bihf[n] + bhhf[n]) : (bihb[n - 1024] + bhhb[n - 1024]);
    }
  }
}

// ---------------- K1: xg = X @ Wih^T + bias  (M=32768,K=320,N=2048) ----------------
__global__ void gemm_xg_kernel(const ushort* __restrict__ X, const ushort* __restrict__ Wih,
                               const float* __restrict__ bias, ushort* __restrict__ xg) {
  __shared__ ushort a_lds[2][128 * 32];
  const int tid = threadIdx.x;
  const int lane = tid & 63, w = tid >> 6;
  const int wr = w >> 1, wc = w & 1;
  const int qrow = lane >> 4, ln = lane & 15;
  const int m0 = blockIdx.x * 128, n0 = blockIdx.y * 128;

  auto stage = [&](int buf, int kt) {
#pragma unroll
    for (int q = 0; q < 2; ++q) {
      int byteoff = w * 2048 + q * 1024 + lane * 16;
      int row = byteoff >> 6, koff = byteoff & 63;
      const char* src = (const char*)X + (long)(m0 + row) * 640 + kt * 64 + koff;
      void* dst = (char*)&a_lds[buf][0] + w * 2048 + q * 1024;  // wave-uniform base
      gload_lds16(src, dst);
    }
  };

  // B fragment base for this lane (row-major Wih, K=320)
  const ushort* wb = Wih + (long)(n0 + wc * 64 + ln) * 320 + qrow * 8;
  auto loadB = [&](short8 (&dst)[4], int kt) {
#pragma unroll
    for (int nt = 0; nt < 4; ++nt)
      dst[nt] = *(const short8*)(wb + nt * 16 * 320 + kt * 32);
  };

  const f32x4 fzero = {0.f, 0.f, 0.f, 0.f};
  f32x4 acc[4][4];
#pragma unroll
  for (int i = 0; i < 4; ++i)
#pragma unroll
    for (int jj = 0; jj < 4; ++jj) acc[i][jj] = fzero;

  auto gemmK = [&](short8 (&b)[4], int buf) {
    short8 a[4];
#pragma unroll
    for (int rt = 0; rt < 4; ++rt)
      a[rt] = *(const short8*)&a_lds[buf][(wr * 64 + rt * 16 + ln) * 32 + qrow * 8];
#pragma unroll
    for (int rt = 0; rt < 4; ++rt)
#pragma unroll
      for (int nt = 0; nt < 4; ++nt)
        acc[rt][nt] = __builtin_amdgcn_mfma_f32_16x16x32_bf16(a[rt], b[nt], acc[rt][nt], 0, 0, 0);
  };

  short8 bA[4], bB[4];
  stage(0, 0);
  loadB(bA, 0);
#pragma unroll 1
  for (int kt2 = 0; kt2 < 5; ++kt2) {
    const int kt = kt2 * 2;
    __syncthreads();                  // stage(kt) landed everywhere (implicit vmcnt drain)
    loadB(bB, kt + 1);                // b-loads FIRST (oldest in queue -> retire unblocked)
    __builtin_amdgcn_sched_barrier(0);
    if (kt < 9) stage(1, kt + 1);     // stage issued AFTER b-loads (in-order vmcnt retirement)
    __builtin_amdgcn_sched_barrier(0);
    gemmK(bA, 0);
    __syncthreads();                  // stage(kt+1) landed
    if (kt2 < 4) loadB(bA, kt + 2);
    __builtin_amdgcn_sched_barrier(0);
    if (kt + 2 < 10) stage(0, kt + 2);
    __builtin_amdgcn_sched_barrier(0);
    gemmK(bB, 1);
  }

  // epilogue: repack through LDS (reuse a_lds[0]) -> coalesced dwordx4 stores
  ushort* sbuf = &a_lds[0][0];   // 32 x 128 ushort = 8 KB per chunk
  float bv[4];
#pragma unroll
  for (int nt = 0; nt < 4; ++nt) bv[nt] = bias[n0 + wc * 64 + nt * 16 + ln];
#pragma unroll
  for (int R = 0; R < 4; ++R) {
    __syncthreads();   // previous chunk's reads done / k-loop reads done
#pragma unroll
    for (int nt = 0; nt < 4; ++nt)
#pragma unroll
      for (int r = 0; r < 4; ++r)
        sbuf[(wr * 16 + qrow * 4 + r) * 128 + wc * 64 + nt * 16 + ln] = f2bf(acc[R][nt][r] + bv[nt]);
    __syncthreads();
#pragma unroll
    for (int p = 0; p < 2; ++p) {
      int row = p * 16 + (tid >> 4);
      int c0 = (tid & 15) * 8;
      uint4w v = *(uint4w*)&sbuf[row * 128 + c0];
      *(uint4w*)&xg[(long)(m0 + (row >> 4) * 64 + R * 16 + (row & 15)) * 2048 + n0 + c0] = v;
    }
  }
}

// ---------------- K2: fused masked LSTM recurrence, one direction per block ----------------
// grid 256 = {d in 0..1} x {cg in 0..127}; 32 columns per block; 512 threads (8 waves)
// Key scheduling rule: xg stage ops are issued AFTER all Whh b-loads each step —
// vmcnt retires in order, so b-load waits must not queue behind the slow 64 KB stage.
__global__ __launch_bounds__(512, 2) void lstm_kernel(const ushort* __restrict__ xg,
                                                      const ushort* __restrict__ Whh,
                                                      float* __restrict__ out) {
  __shared__ ushort h_lds[32][264];          // [col][hid], padded
  __shared__ ushort xg_lds[2][32][1024];     // double-buffered step tile (128 KB)
  const int tid = threadIdx.x;
  const int lane = tid & 63, w = tid >> 6;   // w = hid-slice owner (32 hid per wave)
  const int qrow = lane >> 4, ln = lane & 15;
  const int bid = blockIdx.x;
  const int d = bid >> 7, cg = bid & 127;

  // per-lane base into Whh; fragment (ks,g,q) at +g*65536 + q*4096 + ks*32 elements
  const ushort* wbase = Whh + (long)(d * 1024 + w * 32 + ln) * 256 + qrow * 8;

  float c_st[2][2][4], h_st[2][2][4];
#pragma unroll
  for (int rt = 0; rt < 2; ++rt)
#pragma unroll
    for (int q = 0; q < 2; ++q)
#pragma unroll
      for (int r = 0; r < 4; ++r) { c_st[rt][q][r] = 0.f; h_st[rt][q][r] = 0.f; }

  auto stage = [&](int buf, int j) {
#pragma unroll
    for (int q = 0; q < 8; ++q) {
      int byteoff = w * 8192 + q * 1024 + lane * 16;
      int cloc = byteoff >> 11, noff = byteoff & 2047;
      const char* src = (const char*)xg + (long)((cg * 32 + cloc) * 8 + j) * 4096 + d * 2048 + noff;
      void* dst = (char*)&xg_lds[0][0][0] + buf * 65536 + w * 8192 + q * 1024;  // wave-uniform
      gload_lds16(src, dst);
    }
  };

  const f32x4 fzero = {0.f, 0.f, 0.f, 0.f};

  stage(0, d ? 7 : 0);

#pragma unroll 1
  for (int it = 0; it < 8; ++it) {
    __syncthreads();   // implicit full drain: stage(it) landed everywhere; h_lds(it-1) visible
    const int buf = it & 1;

    f32x4 acc[4][2][2];  // [gate][q(hid-16-block)][row-tile]
#pragma unroll
    for (int g = 0; g < 4; ++g)
#pragma unroll
      for (int q = 0; q < 2; ++q)
#pragma unroll
        for (int rt = 0; rt < 2; ++rt) acc[g][q][rt] = fzero;

    if (it > 0) {  // h==0 at it==0, skip GEMM
      auto loadB = [&](short8 (&dst)[4][2], int ks) {
#pragma unroll
        for (int g = 0; g < 4; ++g)
#pragma unroll
          for (int q = 0; q < 2; ++q)
            dst[g][q] = *(const short8*)(wbase + g * 65536 + q * 4096 + ks * 32);
      };
      auto gemmK = [&](short8 (&b)[4][2], int ks) {
        short8 a0 = *(const short8*)&h_lds[ln][ks * 32 + qrow * 8];
        short8 a1 = *(const short8*)&h_lds[16 + ln][ks * 32 + qrow * 8];
#pragma unroll
        for (int g = 0; g < 4; ++g)
#pragma unroll
          for (int q = 0; q < 2; ++q) {
            acc[g][q][0] = __builtin_amdgcn_mfma_f32_16x16x32_bf16(a0, b[g][q], acc[g][q][0], 0, 0, 0);
            acc[g][q][1] = __builtin_amdgcn_mfma_f32_16x16x32_bf16(a1, b[g][q], acc[g][q][1], 0, 0, 0);
          }
      };
      // 2-deep software pipeline over ks, statically-indexed ping-pong buffers
      short8 bA[4][2], bB[4][2];
      loadB(bA, 0);
      loadB(bB, 1);
      gemmK(bA, 0); loadB(bA, 2);
      gemmK(bB, 1); loadB(bB, 3);
      gemmK(bA, 2); loadB(bA, 4);
      gemmK(bB, 3); loadB(bB, 5);
      gemmK(bA, 4); loadB(bA, 6);
      gemmK(bB, 5); loadB(bB, 7);
      gemmK(bA, 6);
      gemmK(bB, 7);
    }

    // issue next step's xg stage AFTER all b-loads (fenced both sides)
    __builtin_amdgcn_sched_barrier(0);
    if (it < 7) stage((it + 1) & 1, d ? (6 - it) : (it + 1));
    __builtin_amdgcn_sched_barrier(0);

    // LDS-only barrier (do NOT drain vmcnt -> keep xg prefetch in flight):
    asm volatile("s_waitcnt lgkmcnt(0)" ::: "memory");
    __builtin_amdgcn_s_barrier();

    // cell: lane holds all 4 gates of its cells (cc = rt*16+qrow*4+r, hid = w*32+q*16+ln)
    const bool mstep = d ? (it == 0) : (it == 7);
#pragma unroll
    for (int rt = 0; rt < 2; ++rt)
#pragma unroll
      for (int q = 0; q < 2; ++q)
#pragma unroll
        for (int r = 0; r < 4; ++r) {
          int cc = rt * 16 + qrow * 4 + r;
          int hid = w * 32 + q * 16 + ln;
          float pi = acc[0][q][rt][r] + bf2f(xg_lds[buf][cc][hid]);
          float pf = acc[1][q][rt][r] + bf2f(xg_lds[buf][cc][256 + hid]);
          float pg = acc[2][q][rt][r] + bf2f(xg_lds[buf][cc][512 + hid]);
          float po = acc[3][q][rt][r] + bf2f(xg_lds[buf][cc][768 + hid]);
          float cn = sigm(pf) * c_st[rt][q][r] + sigm(pi) * tanh_(pg);
          float hn = sigm(po) * tanh_(cn);
          bool skip = mstep && (cg == 0) && (cc == 0);  // only masked cell: col 0, j==7
          if (!skip) { c_st[rt][q][r] = cn; h_st[rt][q][r] = hn; }
          h_lds[cc][hid] = f2bf(h_st[rt][q][r]);
        }
  }

#pragma unroll
  for (int rt = 0; rt < 2; ++rt)
#pragma unroll
    for (int q = 0; q < 2; ++q)
#pragma unroll
      for (int r = 0; r < 4; ++r) {
        int cc = rt * 16 + qrow * 4 + r;
        int hid = w * 32 + q * 16 + ln;
        out[(long)(cg * 32 + cc) * 512 + d * 256 + hid] = h_st[rt][q][r];
      }
}

extern "C" void kernel_launch(void* const* d_in, const int* in_sizes, int n_in,
                              void* d_out, int out_size, void* d_ws, size_t ws_size,
                              hipStream_t stream) {
  const float* emb  = (const float*)d_in[0];
  const float* wihf = (const float*)d_in[1];
  const float* whhf = (const float*)d_in[2];
  const float* bihf = (const float*)d_in[3];
  const float* bhhf = (const float*)d_in[4];
  const float* wihb = (const float*)d_in[5];
  const float* whhb = (const float*)d_in[6];
  const float* bihb = (const float*)d_in[7];
  const float* bhhb = (const float*)d_in[8];
  const int*   seq  = (const int*)d_in[9];
  float* out = (float*)d_out;

  char* ws = (char*)d_ws;
  // ws layout (bytes): xg 134217728 | X 20971520 | Wih 1310720 | Whh 1048576 | bias 8192
  ushort* xg   = (ushort*)(ws);
  ushort* X    = (ushort*)(ws + 134217728);
  ushort* Wih  = (ushort*)(ws + 155189248);
  ushort* Whh  = (ushort*)(ws + 156499968);
  float*  bias = (float*)(ws + 157548544);

  prep_kernel<<<dim3(1024), dim3(256), 0, stream>>>(emb, wihf, whhf, bihf, bhhf,
                                                    wihb, whhb, bihb, bhhb, seq,
                                                    X, Wih, Whh, bias);
  gemm_xg_kernel<<<dim3(256, 16), dim3(256), 0, stream>>>(X, Wih, bias, xg);
  lstm_kernel<<<dim3(256), dim3(512), 0, stream>>>(xg, Whh, out);
}

// Round 8
// 271.773 us; speedup vs baseline: 1.0304x; 1.0169x over previous
//
#include <hip/hip_runtime.h>

typedef unsigned int uint;
typedef unsigned short ushort;
typedef __attribute__((ext_vector_type(8))) short short8;
typedef __attribute__((ext_vector_type(4))) float f32x4;
typedef __attribute__((ext_vector_type(4))) uint uint4w;

#define T_LEN 32768
#define EMB 300
#define HID 256
#define NCOLS 4096

__device__ __forceinline__ ushort f2bf(float f) {
  uint u = __float_as_uint(f);
  return (ushort)((u + 0x7fffu + ((u >> 16) & 1u)) >> 16);
}
__device__ __forceinline__ float bf2f(ushort u) {
  return __uint_as_float(((uint)u) << 16);
}
__device__ __forceinline__ float sigm(float x) { return 1.f / (1.f + __expf(-x)); }
__device__ __forceinline__ float tanh_(float x) { return 2.f / (1.f + __expf(-2.f * x)) - 1.f; }

__device__ __forceinline__ void gload_lds16(const void* g, void* l) {
  __builtin_amdgcn_global_load_lds((const __attribute__((address_space(1))) void*)g,
                                   (__attribute__((address_space(3))) void*)l, 16, 0, 0);
}

// ---------------- prep: bf16 conversions + embedding gather ----------------
// Whh is written PRE-SWIZZLED for the lstm staging pipeline:
//   Whh2[d][s(16)][c(4)][r(512)][e(8)] = whh_d[gp*512 + r][ks*32 + c*8 + e],  s = ks*2+gp
// -> each 32 KB slice is a contiguous block (coalesced global_load_lds), and the
//    LDS chunk-major layout makes the B-fragment ds_read_b128 conflict-free.
__global__ void prep_kernel(const float* __restrict__ emb,
                            const float* __restrict__ wihf, const float* __restrict__ whhf,
                            const float* __restrict__ bihf, const float* __restrict__ bhhf,
                            const float* __restrict__ wihb, const float* __restrict__ whhb,
                            const float* __restrict__ bihb, const float* __restrict__ bhhb,
                            const int* __restrict__ seq,
                            ushort* __restrict__ X, ushort* __restrict__ Wih,
                            ushort* __restrict__ Whh2, float* __restrict__ bias) {
  const int NX = T_LEN * 40;      // 32768 rows x 40 groups of 8 k (K padded to 320)
  const int NWIH = 2048 * 40;
  const int NWHH = 2048 * 32;
  const int NB = 2048;
  const int total = NX + NWIH + NWHH + NB;
  for (int t = blockIdx.x * blockDim.x + threadIdx.x; t < total; t += gridDim.x * blockDim.x) {
    if (t < NX) {
      int r = t / 40, k8 = t % 40, k = k8 * 8;
      int col = r >> 3, j = r & 7;
      int tok = (col == 0) ? j : (col * 8 - 1 + j);   // matches reference idx
      const float* src = emb + (long)seq[tok] * EMB + k;
      alignas(16) ushort tmp[8];
#pragma unroll
      for (int i = 0; i < 8; ++i) tmp[i] = (k + i < EMB) ? f2bf(src[i]) : (ushort)0;
      *(uint4w*)(X + (long)r * 320 + k) = *(const uint4w*)tmp;
    } else if (t < NX + NWIH) {
      int t2 = t - NX;
      int n = t2 / 40, k8 = t2 % 40, k = k8 * 8;
      const float* src = ((n < 1024) ? wihf : wihb) + (long)(n & 1023) * EMB + k;
      alignas(16) ushort tmp[8];
#pragma unroll
      for (int i = 0; i < 8; ++i) tmp[i] = (k + i < EMB) ? f2bf(src[i]) : (ushort)0;
      *(uint4w*)(Wih + (long)n * 320 + k) = *(const uint4w*)tmp;
    } else if (t < NX + NWIH + NWHH) {
      int t3 = t - NX - NWIH;
      int n = t3 / 32, k8 = t3 % 32;
      int dd = n >> 10, rowg = n & 1023;
      int gp = rowg >> 9, rr = rowg & 511;
      int s = (k8 >> 2) * 2 + gp, c = k8 & 3;
      const float* src = ((dd == 0) ? whhf : whhb) + (long)rowg * HID + k8 * 8;
      alignas(16) ushort tmp[8];
#pragma unroll
      for (int i = 0; i < 8; ++i) tmp[i] = f2bf(src[i]);
      *(uint4w*)(Whh2 + ((((long)dd * 16 + s) * 4 + c) * 512 + rr) * 8) = *(const uint4w*)tmp;
    } else {
      int n = t - NX - NWIH - NWHH;
      bias[n] = (n < 1024) ? (bihf[n] + bhhf[n]) : (bihb[n - 1024] + bhhb[n - 1024]);
    }
  }
}

// ---------------- K1: xg = X @ Wih^T + bias  (M=32768,K=320,N=2048) ----------------
__global__ void gemm_xg_kernel(const ushort* __restrict__ X, const ushort* __restrict__ Wih,
                               const float* __restrict__ bias, ushort* __restrict__ xg) {
  __shared__ ushort a_lds[2][128 * 32];
  const int tid = threadIdx.x;
  const int lane = tid & 63, w = tid >> 6;
  const int wr = w >> 1, wc = w & 1;
  const int qrow = lane >> 4, ln = lane & 15;
  const int m0 = blockIdx.x * 128, n0 = blockIdx.y * 128;

  auto stage = [&](int buf, int kt) {
#pragma unroll
    for (int q = 0; q < 2; ++q) {
      int byteoff = w * 2048 + q * 1024 + lane * 16;
      int row = byteoff >> 6, koff = byteoff & 63;
      const char* src = (const char*)X + (long)(m0 + row) * 640 + kt * 64 + koff;
      void* dst = (char*)&a_lds[buf][0] + w * 2048 + q * 1024;  // wave-uniform base
      gload_lds16(src, dst);
    }
  };

  const ushort* wb = Wih + (long)(n0 + wc * 64 + ln) * 320 + qrow * 8;
  auto loadB = [&](short8 (&dst)[4], int kt) {
#pragma unroll
    for (int nt = 0; nt < 4; ++nt)
      dst[nt] = *(const short8*)(wb + nt * 16 * 320 + kt * 32);
  };

  const f32x4 fzero = {0.f, 0.f, 0.f, 0.f};
  f32x4 acc[4][4];
#pragma unroll
  for (int i = 0; i < 4; ++i)
#pragma unroll
    for (int jj = 0; jj < 4; ++jj) acc[i][jj] = fzero;

  auto gemmK = [&](short8 (&b)[4], int buf) {
    short8 a[4];
#pragma unroll
    for (int rt = 0; rt < 4; ++rt)
      a[rt] = *(const short8*)&a_lds[buf][(wr * 64 + rt * 16 + ln) * 32 + qrow * 8];
#pragma unroll
    for (int rt = 0; rt < 4; ++rt)
#pragma unroll
      for (int nt = 0; nt < 4; ++nt)
        acc[rt][nt] = __builtin_amdgcn_mfma_f32_16x16x32_bf16(a[rt], b[nt], acc[rt][nt], 0, 0, 0);
  };

  short8 bA[4], bB[4];
  stage(0, 0);
  loadB(bA, 0);
#pragma unroll 1
  for (int kt2 = 0; kt2 < 5; ++kt2) {
    const int kt = kt2 * 2;
    __syncthreads();
    loadB(bB, kt + 1);
    __builtin_amdgcn_sched_barrier(0);
    if (kt < 9) stage(1, kt + 1);
    __builtin_amdgcn_sched_barrier(0);
    gemmK(bA, 0);
    __syncthreads();
    if (kt2 < 4) loadB(bA, kt + 2);
    __builtin_amdgcn_sched_barrier(0);
    if (kt + 2 < 10) stage(0, kt + 2);
    __builtin_amdgcn_sched_barrier(0);
    gemmK(bB, 1);
  }

  // epilogue: repack through LDS -> coalesced dwordx4 stores
  ushort* sbuf = &a_lds[0][0];
  float bv[4];
#pragma unroll
  for (int nt = 0; nt < 4; ++nt) bv[nt] = bias[n0 + wc * 64 + nt * 16 + ln];
#pragma unroll
  for (int R = 0; R < 4; ++R) {
    __syncthreads();
#pragma unroll
    for (int nt = 0; nt < 4; ++nt)
#pragma unroll
      for (int r = 0; r < 4; ++r)
        sbuf[(wr * 16 + qrow * 4 + r) * 128 + wc * 64 + nt * 16 + ln] = f2bf(acc[R][nt][r] + bv[nt]);
    __syncthreads();
#pragma unroll
    for (int p = 0; p < 2; ++p) {
      int row = p * 16 + (tid >> 4);
      int c0 = (tid & 15) * 8;
      uint4w v = *(uint4w*)&sbuf[row * 128 + c0];
      *(uint4w*)&xg[(long)(m0 + (row >> 4) * 64 + R * 16 + (row & 15)) * 2048 + n0 + c0] = v;
    }
  }
}

// ---------------- K2: fused masked LSTM recurrence ----------------
// grid 256 = {d} x {cg}; 32 cols/block; 512 threads (8 waves).
// Whh staged per 32-k/gate-pair slice (16 slices/step, 32 KB each) into a 3-buffer
// LDS ring via global_load_lds, 2 slices in flight, counted vmcnt(4) (T3/T4).
// xg read directly per-lane in the cell phase (L3-resident) — no xg LDS.
__global__ __launch_bounds__(512) void lstm_kernel(const ushort* __restrict__ xg,
                                                   const ushort* __restrict__ Whh2,
                                                   float* __restrict__ out) {
  __shared__ ushort h_lds[32][264];                 // [col][hid], padded
  __shared__ alignas(16) char b_lds[3][32768];      // B slice ring
  const int tid = threadIdx.x;
  const int lane = tid & 63, w = tid >> 6;          // w = hid-slice owner (32 hid/wave)
  const int qrow = lane >> 4, ln = lane & 15;
  const int bid = blockIdx.x;
  const int d = bid >> 7, cg = bid & 127;

  for (int i = tid; i < 32 * 264 / 2; i += 512) ((uint*)h_lds)[i] = 0u;

  float c_st[2][2][4], h_st[2][2][4];
#pragma unroll
  for (int rt = 0; rt < 2; ++rt)
#pragma unroll
    for (int q = 0; q < 2; ++q)
#pragma unroll
      for (int r = 0; r < 4; ++r) { c_st[rt][q][r] = 0.f; h_st[rt][q][r] = 0.f; }

  // stage slice s (32 KB, contiguous in Whh2) into b_lds[bufi]; 4 ops/wave
  auto stageB = [&](int s, int bufi) {
    const char* src = (const char*)Whh2 + (((long)(d * 16 + s)) << 15) + w * 4096 + lane * 16;
    char* dst = &b_lds[bufi][0] + w * 4096;   // wave-uniform base
#pragma unroll
    for (int q2 = 0; q2 < 4; ++q2) gload_lds16(src + q2 * 1024, dst + q2 * 1024);
  };

  const f32x4 fzero = {0.f, 0.f, 0.f, 0.f};

#pragma unroll 1
  for (int it = 0; it < 8; ++it) {
    const int j = d ? (7 - it) : it;
    __syncthreads();   // full drain: slices 0,1 landed; h_lds(it-1) visible

    f32x4 acc[4][2][2];  // [gate][q(hid-16-block)][row-tile]
#pragma unroll
    for (int g = 0; g < 4; ++g)
#pragma unroll
      for (int q = 0; q < 2; ++q)
#pragma unroll
        for (int rt = 0; rt < 2; ++rt) acc[g][q][rt] = fzero;

    if (it > 0) {  // h==0 at it==0, skip GEMM
#pragma unroll
      for (int ks = 0; ks < 8; ++ks) {
        short8 a0 = *(const short8*)&h_lds[ln][ks * 32 + qrow * 8];
        short8 a1 = *(const short8*)&h_lds[16 + ln][ks * 32 + qrow * 8];
#pragma unroll
        for (int gp = 0; gp < 2; ++gp) {
          const int s = ks * 2 + gp;
          if (s == 15) { asm volatile("s_waitcnt vmcnt(0)" ::: "memory"); }
          else         { asm volatile("s_waitcnt vmcnt(4)" ::: "memory"); }
          __builtin_amdgcn_s_barrier();
          asm volatile("" ::: "memory");
          if (s <= 13) stageB(s + 2, (s + 2) % 3);
          const char* bb = &b_lds[s % 3][0];
#pragma unroll
          for (int gi = 0; gi < 2; ++gi)
#pragma unroll
            for (int q = 0; q < 2; ++q) {
              short8 b = *(const short8*)(bb + qrow * 8192 + (gi * 256 + w * 32 + q * 16 + ln) * 16);
              const int g = gp * 2 + gi;
              acc[g][q][0] = __builtin_amdgcn_mfma_f32_16x16x32_bf16(a0, b, acc[g][q][0], 0, 0, 0);
              acc[g][q][1] = __builtin_amdgcn_mfma_f32_16x16x32_bf16(a1, b, acc[g][q][1], 0, 0, 0);
            }
        }
      }
    }

    // per-lane xg loads for this step (queue is empty here: issued after last vmcnt(0))
    const ushort* xgb = xg + (long)(cg * 256 + j) * 2048 + qrow * 65536 + d * 1024 + w * 32 + ln;
    ushort xv[2][2][4][4];   // [rt][q][r][g]
#pragma unroll
    for (int rt = 0; rt < 2; ++rt)
#pragma unroll
      for (int q = 0; q < 2; ++q)
#pragma unroll
        for (int r = 0; r < 4; ++r)
#pragma unroll
          for (int g = 0; g < 4; ++g)
            xv[rt][q][r][g] = xgb[(long)rt * 262144 + r * 16384 + g * 256 + q * 16];

    // GEMM <-> cell hazard barrier (LDS only; xg/stage loads stay in flight)
    asm volatile("s_waitcnt lgkmcnt(0)" ::: "memory");
    __builtin_amdgcn_s_barrier();
    asm volatile("" ::: "memory");

    const bool mstep = d ? (it == 0) : (it == 7);
#pragma unroll
    for (int rt = 0; rt < 2; ++rt)
#pragma unroll
      for (int q = 0; q < 2; ++q)
#pragma unroll
        for (int r = 0; r < 4; ++r) {
          int cc = rt * 16 + qrow * 4 + r;
          int hid = w * 32 + q * 16 + ln;
          float pi = acc[0][q][rt][r] + bf2f(xv[rt][q][r][0]);
          float pf = acc[1][q][rt][r] + bf2f(xv[rt][q][r][1]);
          float pg = acc[2][q][rt][r] + bf2f(xv[rt][q][r][2]);
          float po = acc[3][q][rt][r] + bf2f(xv[rt][q][r][3]);
          float cn = sigm(pf) * c_st[rt][q][r] + sigm(pi) * tanh_(pg);
          float hn = sigm(po) * tanh_(cn);
          bool skip = mstep && (cg == 0) && (cc == 0);  // only masked cell: col 0, j==7
          if (!skip) { c_st[rt][q][r] = cn; h_st[rt][q][r] = hn; }
          h_lds[cc][hid] = f2bf(h_st[rt][q][r]);
        }

    // prefetch next step's first two B slices (buffers free: all waves past mfma(15))
    if (it < 7) { stageB(0, 0); stageB(1, 1); }
  }

#pragma unroll
  for (int rt = 0; rt < 2; ++rt)
#pragma unroll
    for (int q = 0; q < 2; ++q)
#pragma unroll
      for (int r = 0; r < 4; ++r) {
        int cc = rt * 16 + qrow * 4 + r;
        int hid = w * 32 + q * 16 + ln;
        out[(long)(cg * 32 + cc) * 512 + d * 256 + hid] = h_st[rt][q][r];
      }
}

extern "C" void kernel_launch(void* const* d_in, const int* in_sizes, int n_in,
                              void* d_out, int out_size, void* d_ws, size_t ws_size,
                              hipStream_t stream) {
  const float* emb  = (const float*)d_in[0];
  const float* wihf = (const float*)d_in[1];
  const float* whhf = (const float*)d_in[2];
  const float* bihf = (const float*)d_in[3];
  const float* bhhf = (const float*)d_in[4];
  const float* wihb = (const float*)d_in[5];
  const float* whhb = (const float*)d_in[6];
  const float* bihb = (const float*)d_in[7];
  const float* bhhb = (const float*)d_in[8];
  const int*   seq  = (const int*)d_in[9];
  float* out = (float*)d_out;

  char* ws = (char*)d_ws;
  // ws layout (bytes): xg 134217728 | X 20971520 | Wih 1310720 | Whh2 1048576 | bias 8192
  ushort* xg   = (ushort*)(ws);
  ushort* X    = (ushort*)(ws + 134217728);
  ushort* Wih  = (ushort*)(ws + 155189248);
  ushort* Whh2 = (ushort*)(ws + 156499968);
  float*  bias = (float*)(ws + 157548544);

  prep_kernel<<<dim3(1024), dim3(256), 0, stream>>>(emb, wihf, whhf, bihf, bhhf,
                                                    wihb, whhb, bihb, bhhb, seq,
                                                    X, Wih, Whh2, bias);
  gemm_xg_kernel<<<dim3(256, 16), dim3(256), 0, stream>>>(X, Wih, bias, xg);
  lstm_kernel<<<dim3(256), dim3(512), 0, stream>>>(xg, Whh2, out);
}